// Round 1
// baseline (1266.096 us; speedup 1.0000x reference)
//
#include <hip/hip_runtime.h>
#include <hip/hip_bf16.h>

typedef short bf16x8 __attribute__((ext_vector_type(8)));
typedef float f32x4 __attribute__((ext_vector_type(4)));
typedef unsigned short u16;

static constexpr int TOK = 65536;        // B*H*W
static constexpr int C = 512;

__device__ __forceinline__ u16 f2bf(float f){
    union { float f; unsigned u; } c; c.f = f;
    return (u16)((c.u + 0x7FFFu + ((c.u >> 16) & 1u)) >> 16);
}

// ---------------- weight transpose: fp32 W[K][N] -> bf16 WT[N][K] ----------------
__global__ __launch_bounds__(256) void wt_kernel(const float* __restrict__ w,
                                                 u16* __restrict__ wt, int K, int N){
    __shared__ float t[32][33];
    int tk = blockIdx.x * 32, tn = blockIdx.y * 32;
    int r = threadIdx.x >> 3, c4 = (threadIdx.x & 7) * 4;
    float4 v = *(const float4*)(w + (size_t)(tk + r) * N + tn + c4);
    t[r][c4 + 0] = v.x; t[r][c4 + 1] = v.y; t[r][c4 + 2] = v.z; t[r][c4 + 3] = v.w;
    __syncthreads();
    ushort4 o;
    o.x = f2bf(t[c4 + 0][r]); o.y = f2bf(t[c4 + 1][r]);
    o.z = f2bf(t[c4 + 2][r]); o.w = f2bf(t[c4 + 3][r]);
    *(ushort4*)(wt + (size_t)(tn + r) * K + tk + c4) = o;
}

// ---------------- LayerNorm (one wave per token), optional shift+window partition ----------------
template<int WINDOWED>
__global__ __launch_bounds__(256) void ln_kernel(const float* __restrict__ x,
                                                 const float* __restrict__ w,
                                                 const float* __restrict__ b,
                                                 u16* __restrict__ out){
    int wid = threadIdx.x >> 6, lane = threadIdx.x & 63;
    int tok = blockIdx.x * 4 + wid;
    const float4* X = (const float4*)(x + (size_t)tok * C);
    float4 v0 = X[lane], v1 = X[lane + 64];
    float s = v0.x + v0.y + v0.z + v0.w + v1.x + v1.y + v1.z + v1.w;
    float q = v0.x*v0.x + v0.y*v0.y + v0.z*v0.z + v0.w*v0.w
            + v1.x*v1.x + v1.y*v1.y + v1.z*v1.z + v1.w*v1.w;
    #pragma unroll
    for (int m = 1; m < 64; m <<= 1){ s += __shfl_xor(s, m, 64); q += __shfl_xor(q, m, 64); }
    float mu = s * (1.f / 512.f);
    float var = q * (1.f / 512.f) - mu * mu;
    float rs = rsqrtf(var + 1e-5f);
    const float4* Wv = (const float4*)w; const float4* Bv = (const float4*)b;
    float4 w0 = Wv[lane], w1 = Wv[lane + 64], b0 = Bv[lane], b1 = Bv[lane + 64];
    size_t dtok;
    if (WINDOWED){
        int bb = tok >> 12, hw = tok & 4095, h = hw >> 6, ww = hw & 63;
        int i = (h + 60) & 63, j = (ww + 60) & 63;   // roll(-4,-4)
        int win = ((i >> 3) << 3) + (j >> 3);
        int n   = ((i & 7) << 3) + (j & 7);
        dtok = ((size_t)(bb * 64 + win) << 6) + n;
    } else dtok = tok;
    u16* o = out + dtok * C;
    ushort4 r0, r1;
    r0.x = f2bf((v0.x - mu) * rs * w0.x + b0.x);
    r0.y = f2bf((v0.y - mu) * rs * w0.y + b0.y);
    r0.z = f2bf((v0.z - mu) * rs * w0.z + b0.z);
    r0.w = f2bf((v0.w - mu) * rs * w0.w + b0.w);
    r1.x = f2bf((v1.x - mu) * rs * w1.x + b1.x);
    r1.y = f2bf((v1.y - mu) * rs * w1.y + b1.y);
    r1.z = f2bf((v1.z - mu) * rs * w1.z + b1.z);
    r1.w = f2bf((v1.w - mu) * rs * w1.w + b1.w);
    *(ushort4*)(o + lane * 4) = r0;
    *(ushort4*)(o + 256 + lane * 4) = r1;
}

// ---------------- GEMM: C[M][N] = A[M][K](bf16) * BT[N][K]^T + bias, fused epilogues ----------------
// MODE 0: qkv scatter -> [win][3][head][n][d] bf16
// MODE 1: proj: window-reverse + unshift + residual(x) -> fp32 x2
// MODE 2: fc1 + exact gelu -> bf16
// MODE 3: fc2 + residual(x2) -> fp32 out
template<int MODE>
__global__ __launch_bounds__(256)
void gemm_kernel(const u16* __restrict__ A, const u16* __restrict__ BT,
                 const float* __restrict__ bias, const float* extra,
                 void* outp, int M, int N, int K){
    __shared__ u16 As[128][72];
    __shared__ u16 Bs[128][72];
    const int nBase = blockIdx.x * 128, mBase = blockIdx.y * 128;
    const int tid = threadIdx.x;
    const int srow = tid >> 3, scol = (tid & 7) * 8;
    const int wid = tid >> 6, lane = tid & 63, lr = lane & 15, lg = lane >> 4;
    const int wRow = (wid >> 1) * 64, wCol = (wid & 1) * 64;
    f32x4 acc[4][4];
    #pragma unroll
    for (int i = 0; i < 4; i++)
        #pragma unroll
        for (int j = 0; j < 4; j++) acc[i][j] = (f32x4){0.f, 0.f, 0.f, 0.f};

    for (int k0 = 0; k0 < K; k0 += 64){
        __syncthreads();
        #pragma unroll
        for (int it = 0; it < 4; it++){
            int r = srow + it * 32;
            *(bf16x8*)(&As[r][scol]) = *(const bf16x8*)(A  + (size_t)(mBase + r) * K + k0 + scol);
            *(bf16x8*)(&Bs[r][scol]) = *(const bf16x8*)(BT + (size_t)(nBase + r) * K + k0 + scol);
        }
        __syncthreads();
        #pragma unroll
        for (int ks = 0; ks < 2; ks++){
            bf16x8 af[4], bf[4];
            #pragma unroll
            for (int mi = 0; mi < 4; mi++) af[mi] = *(const bf16x8*)(&As[wRow + mi * 16 + lr][ks * 32 + lg * 8]);
            #pragma unroll
            for (int ni = 0; ni < 4; ni++) bf[ni] = *(const bf16x8*)(&Bs[wCol + ni * 16 + lr][ks * 32 + lg * 8]);
            #pragma unroll
            for (int mi = 0; mi < 4; mi++)
                #pragma unroll
                for (int ni = 0; ni < 4; ni++)
                    acc[mi][ni] = __builtin_amdgcn_mfma_f32_16x16x32_bf16(af[mi], bf[ni], acc[mi][ni], 0, 0, 0);
        }
    }

    #pragma unroll
    for (int mi = 0; mi < 4; mi++){
        #pragma unroll
        for (int ni = 0; ni < 4; ni++){
            int col = nBase + wCol + ni * 16 + lr;
            float bv = bias[col];
            #pragma unroll
            for (int r = 0; r < 4; r++){
                int row = mBase + wRow + mi * 16 + lg * 4 + r;
                float val = acc[mi][ni][r] + bv;
                if (MODE == 0){
                    int t3 = col >> 9, head = (col >> 5) & 15, d = col & 31;
                    int win = row >> 6, n = row & 63;
                    ((u16*)outp)[((size_t)((win * 3 + t3) * 16 + head)) * 2048 + n * 32 + d] = f2bf(val);
                } else if (MODE == 1){
                    int gwin = row >> 6, n = row & 63;
                    int bb = gwin >> 6, wi = gwin & 63;
                    int sh = ((wi >> 3) << 3) + (n >> 3), sw = ((wi & 7) << 3) + (n & 7);
                    int oh = (sh + 4) & 63, ow = (sw + 4) & 63;
                    size_t tk = ((size_t)bb << 12) + (oh << 6) + ow;
                    ((float*)outp)[tk * 512 + col] = extra[tk * 512 + col] + val;
                } else if (MODE == 2){
                    float g = 0.5f * val * (1.f + erff(val * 0.70710678118654752f));
                    ((u16*)outp)[(size_t)row * 2048 + col] = f2bf(g);
                } else {
                    ((float*)outp)[(size_t)row * 512 + col] = val + extra[(size_t)row * 512 + col];
                }
            }
        }
    }
}

// ---------------- fused window attention: one wave per (window, head) ----------------
__global__ __launch_bounds__(256)
void attn_kernel(const u16* __restrict__ qkv, const float* __restrict__ rel_bias,
                 u16* __restrict__ obuf){
    __shared__ u16 P[4][64][72];
    __shared__ u16 Vt[4][32][72];
    const int wid = threadIdx.x >> 6, lane = threadIdx.x & 63, lr = lane & 15, lg = lane >> 4;
    const int unit = blockIdx.x * 4 + wid;
    const int gwin = unit >> 4, head = unit & 15;
    const u16* qb = qkv + ((size_t)(gwin * 3 + 0) * 16 + head) * 2048;
    const u16* kb = qb + 16 * 2048;
    const u16* vb = qb + 32 * 2048;

    // QK^T (K = HD = 32, one MFMA k-step)
    bf16x8 aq[4], bk[4];
    #pragma unroll
    for (int mi = 0; mi < 4; mi++) aq[mi] = *(const bf16x8*)(qb + (mi * 16 + lr) * 32 + lg * 8);
    #pragma unroll
    for (int ni = 0; ni < 4; ni++) bk[ni] = *(const bf16x8*)(kb + (ni * 16 + lr) * 32 + lg * 8);
    f32x4 s[4][4];
    #pragma unroll
    for (int i = 0; i < 4; i++)
        #pragma unroll
        for (int j = 0; j < 4; j++) s[i][j] = (f32x4){0.f, 0.f, 0.f, 0.f};
    #pragma unroll
    for (int mi = 0; mi < 4; mi++)
        #pragma unroll
        for (int ni = 0; ni < 4; ni++)
            s[mi][ni] = __builtin_amdgcn_mfma_f32_16x16x32_bf16(aq[mi], bk[ni], s[mi][ni], 0, 0, 0);

    // stage V transposed into LDS: Vt[d][j] = v[j][d]
    #pragma unroll
    for (int cb = 0; cb < 4; cb++){
        bf16x8 v = *(const bf16x8*)(vb + lane * 32 + cb * 8);
        #pragma unroll
        for (int e = 0; e < 8; e++) Vt[wid][cb * 8 + e][lane] = (u16)v[e];
    }

    // bias + mask + softmax (rows i spread over (mi, lg, r); cols j over (ni, lr))
    const int wi = gwin & 63, wrow = wi >> 3, wcol = wi & 7;
    int regj[4];
    #pragma unroll
    for (int ni = 0; ni < 4; ni++){
        int jt = ni * 16 + lr;
        int gi = wrow * 8 + (jt >> 3), gj = wcol * 8 + (jt & 7);
        int hr = (gi < 56) ? 0 : ((gi < 60) ? 1 : 2);
        int wr = (gj < 56) ? 0 : ((gj < 60) ? 1 : 2);
        regj[ni] = hr * 3 + wr;
    }
    const float SCALE = 0.17677669529663687f;
    #pragma unroll
    for (int mi = 0; mi < 4; mi++){
        #pragma unroll
        for (int r = 0; r < 4; r++){
            int it = mi * 16 + lg * 4 + r;
            int gi = wrow * 8 + (it >> 3), gj = wcol * 8 + (it & 7);
            int hr = (gi < 56) ? 0 : ((gi < 60) ? 1 : 2);
            int wr = (gj < 56) ? 0 : ((gj < 60) ? 1 : 2);
            int regi = hr * 3 + wr;
            float vv[4];
            float mx = -1e30f;
            #pragma unroll
            for (int ni = 0; ni < 4; ni++){
                int jt = ni * 16 + lr;
                int dr = (it >> 3) - (jt >> 3) + 7;
                int dc = (it & 7) - (jt & 7) + 7;
                float bias = rel_bias[(dr * 15 + dc) * 16 + head];
                float msk = (regi == regj[ni]) ? 0.f : -100.f;
                vv[ni] = s[mi][ni][r] * SCALE + bias + msk;
                mx = fmaxf(mx, vv[ni]);
            }
            #pragma unroll
            for (int m = 1; m < 16; m <<= 1) mx = fmaxf(mx, __shfl_xor(mx, m, 64));
            float sm = 0.f;
            #pragma unroll
            for (int ni = 0; ni < 4; ni++){ vv[ni] = __expf(vv[ni] - mx); sm += vv[ni]; }
            #pragma unroll
            for (int m = 1; m < 16; m <<= 1) sm += __shfl_xor(sm, m, 64);
            float inv = 1.f / sm;
            #pragma unroll
            for (int ni = 0; ni < 4; ni++) s[mi][ni][r] = vv[ni] * inv;
        }
    }

    // P -> LDS (bf16)
    #pragma unroll
    for (int mi = 0; mi < 4; mi++)
        #pragma unroll
        for (int ni = 0; ni < 4; ni++)
            #pragma unroll
            for (int r = 0; r < 4; r++)
                P[wid][mi * 16 + lg * 4 + r][ni * 16 + lr] = f2bf(s[mi][ni][r]);

    asm volatile("s_waitcnt lgkmcnt(0)" ::: "memory");

    // O = P @ V   (K = 64: two k-steps)
    f32x4 oacc[4][2];
    #pragma unroll
    for (int i = 0; i < 4; i++){ oacc[i][0] = (f32x4){0.f,0.f,0.f,0.f}; oacc[i][1] = (f32x4){0.f,0.f,0.f,0.f}; }
    #pragma unroll
    for (int ks = 0; ks < 2; ks++){
        bf16x8 ap[4], bv[2];
        #pragma unroll
        for (int mi = 0; mi < 4; mi++) ap[mi] = *(const bf16x8*)(&P[wid][mi * 16 + lr][ks * 32 + lg * 8]);
        #pragma unroll
        for (int nt = 0; nt < 2; nt++) bv[nt] = *(const bf16x8*)(&Vt[wid][nt * 16 + lr][ks * 32 + lg * 8]);
        #pragma unroll
        for (int mi = 0; mi < 4; mi++)
            #pragma unroll
            for (int nt = 0; nt < 2; nt++)
                oacc[mi][nt] = __builtin_amdgcn_mfma_f32_16x16x32_bf16(ap[mi], bv[nt], oacc[mi][nt], 0, 0, 0);
    }

    u16* ob = obuf + (size_t)gwin * 64 * 512 + head * 32;
    #pragma unroll
    for (int mi = 0; mi < 4; mi++)
        #pragma unroll
        for (int nt = 0; nt < 2; nt++)
            #pragma unroll
            for (int r = 0; r < 4; r++)
                ob[(size_t)(mi * 16 + lg * 4 + r) * 512 + nt * 16 + lr] = f2bf(oacc[mi][nt][r]);
}

extern "C" void kernel_launch(void* const* d_in, const int* in_sizes, int n_in,
                              void* d_out, int out_size, void* d_ws, size_t ws_size,
                              hipStream_t stream){
    const float* x     = (const float*)d_in[0];
    const float* n1w   = (const float*)d_in[1];
    const float* n1b   = (const float*)d_in[2];
    const float* qkvw  = (const float*)d_in[3];
    const float* qkvb  = (const float*)d_in[4];
    const float* relb  = (const float*)d_in[5];
    const float* projw = (const float*)d_in[6];
    const float* projb = (const float*)d_in[7];
    const float* n2w   = (const float*)d_in[8];
    const float* n2b   = (const float*)d_in[9];
    const float* fc1w  = (const float*)d_in[10];
    const float* fc1b  = (const float*)d_in[11];
    const float* fc2w  = (const float*)d_in[12];
    const float* fc2b  = (const float*)d_in[13];
    float* out = (float*)d_out;

    u16* Wqkv  = (u16*)d_ws;                      // 1536*512
    u16* Wproj = Wqkv  + (size_t)1536 * 512;      // 512*512
    u16* Wfc1  = Wproj + (size_t)512 * 512;       // 2048*512
    u16* Wfc2  = Wfc1  + (size_t)2048 * 512;      // 512*2048
    u16* bufH  = Wfc2  + (size_t)512 * 2048;      // TOK*512 bf16
    u16* bufQKV= bufH  + (size_t)TOK * 512;       // TOK*1536 bf16
    u16* bufO  = bufQKV+ (size_t)TOK * 1536;      // TOK*512 bf16
    u16* bufA1 = bufQKV;                          // alias: TOK*2048 bf16 spans QKV+O
    float* x2  = out;                             // x2 lives in d_out

    wt_kernel<<<dim3(512 / 32, 1536 / 32), 256, 0, stream>>>(qkvw, Wqkv, 512, 1536);
    wt_kernel<<<dim3(512 / 32, 512 / 32),  256, 0, stream>>>(projw, Wproj, 512, 512);
    wt_kernel<<<dim3(512 / 32, 2048 / 32), 256, 0, stream>>>(fc1w, Wfc1, 512, 2048);
    wt_kernel<<<dim3(2048 / 32, 512 / 32), 256, 0, stream>>>(fc2w, Wfc2, 2048, 512);

    ln_kernel<1><<<TOK / 4, 256, 0, stream>>>(x, n1w, n1b, bufH);

    gemm_kernel<0><<<dim3(1536 / 128, TOK / 128), 256, 0, stream>>>(bufH, Wqkv, qkvb, nullptr, bufQKV, TOK, 1536, 512);

    attn_kernel<<<(TOK / 64) * 16 / 4, 256, 0, stream>>>(bufQKV, relb, bufO);

    gemm_kernel<1><<<dim3(512 / 128, TOK / 128), 256, 0, stream>>>(bufO, Wproj, projb, x, x2, TOK, 512, 512);

    ln_kernel<0><<<TOK / 4, 256, 0, stream>>>(x2, n2w, n2b, bufH);

    gemm_kernel<2><<<dim3(2048 / 128, TOK / 128), 256, 0, stream>>>(bufH, Wfc1, fc1b, nullptr, bufA1, TOK, 2048, 512);

    gemm_kernel<3><<<dim3(512 / 128, TOK / 128), 256, 0, stream>>>(bufA1, Wfc2, fc2b, x2, out, TOK, 512, 2048);
}